// Round 1
// baseline (7697.016 us; speedup 1.0000x reference)
//
#include <hip/hip_runtime.h>

#define D 128
#define TN 160000
#define NPB 50          // nodes per unit (subgraph or graph)
#define EPB 400         // edges per unit
#define EBIG 1280000    // total subgraph edges
#define EORG 25600      // total original edges
#define NSUB 3200
#define GG 64

// ---------------------------------------------------------------------------
// Fused GraphConv: per-unit LDS edge aggregation + [50,256]x[256,128] GEMM
// + BatchNorm statistics (sum, sumsq) via block-reduced global atomics.
// unit u owns nodes [u*50,(u+1)*50) and edges [u*400,(u+1)*400); by
// construction of setup_inputs all edge endpoints are inside the unit.
// ---------------------------------------------------------------------------
__global__ __launch_bounds__(256, 2)
void conv_kernel(const float* __restrict__ xin,
                 const int* __restrict__ esrc, const int* __restrict__ edst,
                 const float* __restrict__ Wr, const float* __restrict__ Wn,
                 const float* __restrict__ bias,
                 float* __restrict__ out, float* __restrict__ stats)
{
    __shared__ float xs[NPB * D];     // 25.6 KB
    __shared__ float ag[NPB * D];     // 25.6 KB
    __shared__ float wr_t[16 * D];    // 8 KB
    __shared__ float wn_t[16 * D];    // 8 KB
    __shared__ float red[16 * D];     // 8 KB
    __shared__ int els[EPB];
    __shared__ int eld[EPB];

    const int tid = threadIdx.x;
    const int u = blockIdx.x;
    const int nb = u * NPB;
    const int eb = u * EPB;

    // stage x tile, zero agg
    const float4 z4 = make_float4(0.f, 0.f, 0.f, 0.f);
    for (int i = tid; i < NPB * D / 4; i += 256) {
        ((float4*)xs)[i] = ((const float4*)xin)[(size_t)nb * (D / 4) + i];
        ((float4*)ag)[i] = z4;
    }
    for (int i = tid; i < EPB; i += 256) {
        els[i] = esrc[eb + i] - nb;
        eld[i] = edst[eb + i] - nb;
    }
    __syncthreads();

    // edge aggregation: 2 edges in flight x 128 channels, LDS atomics
    {
        const int c = tid & (D - 1);
        const int half = tid >> 7;
        for (int e0 = 0; e0 < EPB; e0 += 2) {
            const int e = e0 + half;
            atomicAdd(&ag[eld[e] * D + c], xs[els[e] * D + c]);
        }
    }
    __syncthreads();

    // GEMM: out[r][j] = sum_k xs[r][k]*Wr[k][j] + ag[r][k]*Wn[k][j] + b[j]
    const int tx = tid & 15;       // 16 col groups of 8
    const int ty = tid >> 4;       // 16 row groups
    const int j0 = tx * 8;
    int rbase[4];
    bool rv[4];
#pragma unroll
    for (int ri = 0; ri < 4; ++ri) {
        const int r = ty + ri * 16;
        rv[ri] = (r < NPB);
        rbase[ri] = (rv[ri] ? r : 0) * D;
    }
    float acc[4][8];
#pragma unroll
    for (int ri = 0; ri < 4; ++ri)
#pragma unroll
        for (int jj = 0; jj < 8; ++jj)
            acc[ri][jj] = bias[j0 + jj];

    for (int kt = 0; kt < 8; ++kt) {
        for (int i = tid; i < 16 * D / 4; i += 256) {
            ((float4*)wr_t)[i] = ((const float4*)(Wr + kt * 16 * D))[i];
            ((float4*)wn_t)[i] = ((const float4*)(Wn + kt * 16 * D))[i];
        }
        __syncthreads();
#pragma unroll
        for (int k = 0; k < 16; ++k) {
            const int kk = kt * 16 + k;
            const float4 w0 = *(const float4*)&wr_t[k * D + j0];
            const float4 w1 = *(const float4*)&wr_t[k * D + j0 + 4];
            const float4 n0 = *(const float4*)&wn_t[k * D + j0];
            const float4 n1 = *(const float4*)&wn_t[k * D + j0 + 4];
#pragma unroll
            for (int ri = 0; ri < 4; ++ri) {
                const float a = xs[rbase[ri] + kk];
                const float g = ag[rbase[ri] + kk];
                acc[ri][0] += a * w0.x + g * n0.x;
                acc[ri][1] += a * w0.y + g * n0.y;
                acc[ri][2] += a * w0.z + g * n0.z;
                acc[ri][3] += a * w0.w + g * n0.w;
                acc[ri][4] += a * w1.x + g * n1.x;
                acc[ri][5] += a * w1.y + g * n1.y;
                acc[ri][6] += a * w1.z + g * n1.z;
                acc[ri][7] += a * w1.w + g * n1.w;
            }
        }
        __syncthreads();
    }

    // write out + BN stat partials
    float psum[8], psq[8];
#pragma unroll
    for (int jj = 0; jj < 8; ++jj) { psum[jj] = 0.f; psq[jj] = 0.f; }
#pragma unroll
    for (int ri = 0; ri < 4; ++ri) {
        if (rv[ri]) {
#pragma unroll
            for (int jj = 0; jj < 8; ++jj) {
                const float v = acc[ri][jj];
                psum[jj] += v;
                psq[jj] += v * v;
            }
            const float4 o0 = make_float4(acc[ri][0], acc[ri][1], acc[ri][2], acc[ri][3]);
            const float4 o1 = make_float4(acc[ri][4], acc[ri][5], acc[ri][6], acc[ri][7]);
            *(float4*)&out[(size_t)nb * D + rbase[ri] + j0] = o0;
            *(float4*)&out[(size_t)nb * D + rbase[ri] + j0 + 4] = o1;
        }
    }
#pragma unroll
    for (int jj = 0; jj < 8; ++jj) red[ty * D + j0 + jj] = psum[jj];
    __syncthreads();
    if (tid < D) {
        float s = 0.f;
#pragma unroll
        for (int t = 0; t < 16; ++t) s += red[t * D + tid];
        atomicAdd(&stats[tid], s);
    }
    __syncthreads();
#pragma unroll
    for (int jj = 0; jj < 8; ++jj) red[ty * D + j0 + jj] = psq[jj];
    __syncthreads();
    if (tid < D) {
        float s = 0.f;
#pragma unroll
        for (int t = 0; t < 16; ++t) s += red[t * D + tid];
        atomicAdd(&stats[D + tid], s);
    }
}

// x_sum[g*50+n][c] = mean over s of x[g*2500 + s*50 + n][c]
__global__ void xsum_kernel(const float* __restrict__ xin, float* __restrict__ xsum)
{
    const int t = blockIdx.x * 256 + threadIdx.x;   // 409600 total
    const int orig = t >> 7;
    const int c = t & (D - 1);
    const int g = orig / 50;
    const int n = orig - g * 50;
    const float* p = xin + ((size_t)(g * 2500 + n)) * D + c;
    float s = 0.f;
#pragma unroll 5
    for (int si = 0; si < 50; ++si) s += p[(size_t)si * 50 * D];
    xsum[t] = s / 50.0f;
}

// finalize BN params: prm = [a1, c1, a2, c2] per channel; re-zero stats
__global__ void bnfin_kernel(float* __restrict__ stats,
                             const float* __restrict__ bng, const float* __restrict__ bnb,
                             const float* __restrict__ bnsg, const float* __restrict__ bnsb,
                             float* __restrict__ prm)
{
    const int tid = threadIdx.x;
    if (tid < D) {
        const float s = stats[tid], q = stats[D + tid];
        const float mu = s / (float)TN;
        const float var = q / (float)TN - mu * mu;
        const float inv = 1.0f / sqrtf(var + 1e-5f);
        const float a = bng[tid] * inv;
        prm[tid] = a;
        prm[D + tid] = bnb[tid] - mu * a;
    } else {
        const int c = tid - D;
        const float s = stats[2 * D + c], q = stats[3 * D + c];
        const float mu = s / (float)NSUB;
        const float var = q / (float)NSUB - mu * mu;
        const float inv = 1.0f / sqrtf(var + 1e-5f);
        const float a = bnsg[c] * inv;
        prm[2 * D + c] = a;
        prm[3 * D + c] = bnsb[c] - mu * a;
    }
    __syncthreads();
    stats[tid] = 0.f;
    stats[256 + tid] = 0.f;
}

// x = relu(a1*h1 + c1 + a2*h2[node_idx] + c2), in place into h1
__global__ void fuse_kernel(float* __restrict__ h1, const float* __restrict__ h2,
                            const float* __restrict__ prm)
{
    const int t = blockIdx.x * 256 + threadIdx.x;   // 5,120,000 float4s
    const int row = t >> 5;
    const int c0 = (t & 31) * 4;
    const unsigned g = (unsigned)row / 2500u;
    const int ni = (int)g * 50 + (int)((unsigned)row % 50u);
    const float4 h1v = ((const float4*)h1)[t];
    const float4 a1 = *(const float4*)&prm[c0];
    const float4 c1 = *(const float4*)&prm[D + c0];
    const float4 a2 = *(const float4*)&prm[2 * D + c0];
    const float4 c2 = *(const float4*)&prm[3 * D + c0];
    const float4 h2v = *(const float4*)&h2[(size_t)ni * D + c0];
    float4 r;
    r.x = fmaxf(0.f, a1.x * h1v.x + c1.x + a2.x * h2v.x + c2.x);
    r.y = fmaxf(0.f, a1.y * h1v.y + c1.y + a2.y * h2v.y + c2.y);
    r.z = fmaxf(0.f, a1.z * h1v.z + c1.z + a2.z * h2v.z + c2.z);
    r.w = fmaxf(0.f, a1.w * h1v.w + c1.w + a2.w * h2v.w + c2.w);
    ((float4*)h1)[t] = r;
}

// hierarchical mean pooling: (sum 50 nodes)/50 per subgraph, then /50 per graph
__global__ void pool_kernel(const float* __restrict__ x, float* __restrict__ hg)
{
    __shared__ float red[2 * D];
    const int g = blockIdx.x;
    const int c = threadIdx.x & (D - 1);
    const int h = threadIdx.x >> 7;
    float tot = 0.f;
    for (int s = h * 25; s < h * 25 + 25; ++s) {
        const float* p = x + ((size_t)g * 2500 + s * 50) * D + c;
        float ss = 0.f;
#pragma unroll 5
        for (int r = 0; r < 50; ++r) ss += p[(size_t)r * D];
        tot += ss / 50.0f;
    }
    red[h * D + c] = tot;
    __syncthreads();
    if (h == 0) hg[g * D + c] = (red[c] + red[D + c]) / 50.0f;
}

__global__ void mlp_kernel(const float* __restrict__ hg,
                           const float* __restrict__ W1, const float* __restrict__ b1,
                           const float* __restrict__ W2, const float* __restrict__ b2,
                           float* __restrict__ out)
{
    __shared__ float xv[D];
    __shared__ float hid[2 * D];
    const int g = blockIdx.x, tid = threadIdx.x;
    if (tid < D) xv[tid] = hg[g * D + tid];
    __syncthreads();
    float a = b1[tid];
    for (int k = 0; k < D; ++k) a += xv[k] * W1[k * 2 * D + tid];
    hid[tid] = fmaxf(a, 0.f);
    __syncthreads();
    if (tid < 10) {
        float o = b2[tid];
        for (int k = 0; k < 2 * D; ++k) o += hid[k] * W2[k * 10 + tid];
        out[g * 10 + tid] = o;
    }
}

__global__ void zero_kernel(float* __restrict__ p, int n)
{
    const int t = blockIdx.x * 256 + threadIdx.x;
    if (t < n) p[t] = 0.f;
}

extern "C" void kernel_launch(void* const* d_in, const int* in_sizes, int n_in,
                              void* d_out, int out_size, void* d_ws, size_t ws_size,
                              hipStream_t stream)
{
    const float* x0   = (const float*)d_in[0];
    const float* Wr   = (const float*)d_in[1];
    const float* Wn   = (const float*)d_in[2];
    const float* bb   = (const float*)d_in[3];
    const float* bng  = (const float*)d_in[4];
    const float* bnb  = (const float*)d_in[5];
    const float* Wsr  = (const float*)d_in[6];
    const float* Wsn  = (const float*)d_in[7];
    const float* bs   = (const float*)d_in[8];
    const float* bnsg = (const float*)d_in[9];
    const float* bnsb = (const float*)d_in[10];
    const float* fW1  = (const float*)d_in[11];
    const float* fb1  = (const float*)d_in[12];
    const float* fW2  = (const float*)d_in[13];
    const float* fb2  = (const float*)d_in[14];
    const int* ei     = (const int*)d_in[15];
    const int* oei    = (const int*)d_in[16];
    float* out        = (float*)d_out;

    float* ws = (float*)d_ws;
    const size_t BIG = (size_t)TN * D;          // 20,480,000 floats
    float* bufs[2] = { ws, ws + BIG };
    float* xsumb = ws + 2 * BIG;                // 409,600
    float* h2b   = xsumb + (size_t)NSUB * D;    // 409,600
    float* stats = h2b + (size_t)NSUB * D;      // 512
    float* prm   = stats + 512;                 // 512
    float* hg    = prm + 512;                   // 8,192

    zero_kernel<<<2, 256, 0, stream>>>(stats, 512);

    const float* xi = x0;
    for (int i = 0; i < 4; ++i) {
        float* hb = bufs[i & 1];
        conv_kernel<<<NSUB, 256, 0, stream>>>(xi, ei, ei + EBIG,
                                              Wr + (size_t)i * D * D, Wn + (size_t)i * D * D,
                                              bb + i * D, hb, stats);
        xsum_kernel<<<NSUB * D / 256, 256, 0, stream>>>(xi, xsumb);
        conv_kernel<<<GG, 256, 0, stream>>>(xsumb, oei, oei + EORG,
                                            Wsr + (size_t)i * D * D, Wsn + (size_t)i * D * D,
                                            bs + i * D, h2b, stats + 256);
        bnfin_kernel<<<1, 256, 0, stream>>>(stats, bng + i * D, bnb + i * D,
                                            bnsg + i * D, bnsb + i * D, prm);
        fuse_kernel<<<TN * D / 4 / 256, 256, 0, stream>>>(hb, h2b, prm);
        xi = hb;
    }

    pool_kernel<<<GG, 256, 0, stream>>>(xi, hg);
    mlp_kernel<<<GG, 256, 0, stream>>>(hg, fW1, fb1, fW2, fb2, out);
}

// Round 2
// 1060.249 us; speedup vs baseline: 7.2596x; 7.2596x over previous
//
#include <hip/hip_runtime.h>
#include <stdint.h>

#define D 128
#define TN 160000
#define NSUB 3200
#define GG 64
#define NL 4

typedef __bf16 bf16x8 __attribute__((ext_vector_type(8)));
typedef float f32x4 __attribute__((ext_vector_type(4)));
typedef unsigned int u32x4 __attribute__((ext_vector_type(4)));

__device__ __forceinline__ unsigned short f2bf(float v) {
    union { float f; uint32_t u; } c; c.f = v;
    uint32_t r = c.u + 0x7fffu + ((c.u >> 16) & 1u);
    return (unsigned short)(r >> 16);
}
__device__ __forceinline__ float bf2f(unsigned short h) {
    union { float f; uint32_t u; } c; c.u = ((uint32_t)h) << 16;
    return c.f;
}

__device__ __forceinline__ void gload16(const void* g, void* l) {
    __builtin_amdgcn_global_load_lds(
        (const __attribute__((address_space(1))) unsigned int*)g,
        (__attribute__((address_space(3))) unsigned int*)l, 16, 0, 0);
}

// ---------------------------------------------------------------------------
// Fused GraphConv via MFMA: block = 2 units (100 rows, padded to 112) x 256 cols.
// A3: [M][256] bf16 rows = [hi(128) | lo(128)] of x.
// W3T: [256 n][384 k] bf16, k-blocks = [W_hi | W_hi | W_lo] columns (k-major).
// Virtual K = 384 : hi*Whi + lo*Whi + hi*Wlo  ~= fp32 GEMM.
// Epilogue: Yn (cols 128:256) -> LDS, CSR aggregation per unit,
// H = Yr + agg + bias -> global; BN sum/sumsq -> atomics.
// ---------------------------------------------------------------------------
__global__ __launch_bounds__(256, 2)
void gconv_kernel(const unsigned short* __restrict__ A3,
                  const unsigned short* __restrict__ W3T,
                  const float* __restrict__ bias,
                  const int* __restrict__ rp,
                  const unsigned char* __restrict__ colx,
                  float* __restrict__ H,
                  float* __restrict__ stats)
{
    __shared__ __align__(16) unsigned short Alds[112 * 32];   // 7 KB
    __shared__ __align__(16) unsigned short Blds[256 * 32];   // 16 KB
    __shared__ float agg[100 * 132];                          // 52.8 KB
    __shared__ int rpl[102];
    __shared__ unsigned char coll[800];

    const int tid = threadIdx.x;
    const int blk = blockIdx.x;
    const int rowbase = blk * 100;
    const int lane = tid & 63, wv = tid >> 6;
    const int p = lane & 15, q = lane >> 4;
    const int wn0 = wv * 64;

    // zero the 12 pad rows of Alds (rows 100..111 stay zero all k-steps)
    if (tid < 192) ((float*)(Alds + 100 * 32))[tid] = 0.f;
    if (tid < 102) rpl[tid] = rp[blk * 102 + tid];
    if (tid < 200) ((uint32_t*)coll)[tid] = ((const uint32_t*)(colx + (size_t)blk * 800))[tid];

    f32x4 acc[7][4];
#pragma unroll
    for (int i = 0; i < 7; ++i)
#pragma unroll
        for (int j = 0; j < 4; ++j) acc[i][j] = (f32x4){0.f, 0.f, 0.f, 0.f};

    for (int s = 0; s < 12; ++s) {
        const int ka = (s < 4) ? s * 32 : (s < 8) ? 128 + (s - 4) * 32 : (s - 8) * 32;
        const int kw = s * 32;
        // stage A tile: 400 chunks of 16B (100 rows x 64B)
        {
            int c = tid;
            int r = c >> 2, qq = c & 3;
            gload16(A3 + (size_t)(rowbase + r) * 256 + ka + qq * 8, Alds + c * 8);
        }
        if (tid < 144) {
            int c = 256 + tid;
            int r = c >> 2, qq = c & 3;
            gload16(A3 + (size_t)(rowbase + r) * 256 + ka + qq * 8, Alds + c * 8);
        }
        // stage B tile: 1024 chunks (256 n-rows x 64B)
#pragma unroll
        for (int rr = 0; rr < 4; ++rr) {
            int c = rr * 256 + tid;
            int n = c >> 2, qq = c & 3;
            gload16(W3T + (size_t)n * 384 + kw + qq * 8, Blds + c * 8);
        }
        __syncthreads();

        bf16x8 bfr[4];
#pragma unroll
        for (int ni = 0; ni < 4; ++ni) {
            u32x4 raw = *(const u32x4*)&Blds[(wn0 + ni * 16 + p) * 32 + q * 8];
            bfr[ni] = __builtin_bit_cast(bf16x8, raw);
        }
#pragma unroll
        for (int mi = 0; mi < 7; ++mi) {
            u32x4 raw = *(const u32x4*)&Alds[(mi * 16 + p) * 32 + q * 8];
            bf16x8 afr = __builtin_bit_cast(bf16x8, raw);
#pragma unroll
            for (int ni = 0; ni < 4; ++ni)
                acc[mi][ni] = __builtin_amdgcn_mfma_f32_16x16x32_bf16(afr, bfr[ni], acc[mi][ni], 0, 0, 0);
        }
        __syncthreads();
    }

    // ---- epilogue ----
    // waves 2,3 hold Yn (cols 128:256): dump to agg LDS
    if (wv >= 2) {
#pragma unroll
        for (int mi = 0; mi < 7; ++mi)
#pragma unroll
            for (int r = 0; r < 4; ++r) {
                const int row = mi * 16 + q * 4 + r;
                if (row < 100) {
#pragma unroll
                    for (int ni = 0; ni < 4; ++ni)
                        agg[row * 132 + (wn0 - 128) + ni * 16 + p] = acc[mi][ni][r];
                }
            }
    }
    __syncthreads();

    // waves 0,1 hold Yr (cols 0:128): CSR aggregate + bias, write H
    if (wv < 2) {
#pragma unroll
        for (int mi = 0; mi < 7; ++mi)
#pragma unroll
            for (int r = 0; r < 4; ++r) {
                const int row = mi * 16 + q * 4 + r;
                if (row >= 100) continue;
                const int ul = row >= 50 ? 1 : 0;
                const int dl = row - ul * 50;
                const int e0 = rpl[ul * 51 + dl], e1 = rpl[ul * 51 + dl + 1];
                float s0 = 0.f, s1 = 0.f, s2 = 0.f, s3 = 0.f;
                for (int e = e0; e < e1; ++e) {
                    const int sr = (int)coll[ul * 400 + e] + ul * 50;
                    s0 += agg[sr * 132 + wn0 + p];
                    s1 += agg[sr * 132 + wn0 + 16 + p];
                    s2 += agg[sr * 132 + wn0 + 32 + p];
                    s3 += agg[sr * 132 + wn0 + 48 + p];
                }
#pragma unroll
                for (int ni = 0; ni < 4; ++ni) {
                    const float sv = (ni == 0) ? s0 : (ni == 1) ? s1 : (ni == 2) ? s2 : s3;
                    const int cc = wn0 + ni * 16 + p;
                    const float h = acc[mi][ni][r] + sv + bias[cc];
                    acc[mi][ni][r] = h;
                    H[(size_t)(rowbase + row) * 128 + cc] = h;
                }
            }
    }
    __syncthreads();
    // waves 0,1 write H into agg (in place, Yn dead) for the stat reduce
    if (wv < 2) {
#pragma unroll
        for (int mi = 0; mi < 7; ++mi)
#pragma unroll
            for (int r = 0; r < 4; ++r) {
                const int row = mi * 16 + q * 4 + r;
                if (row < 100) {
#pragma unroll
                    for (int ni = 0; ni < 4; ++ni)
                        agg[row * 132 + wn0 + ni * 16 + p] = acc[mi][ni][r];
                }
            }
    }
    __syncthreads();
    if (tid < 128) {
        float sm = 0.f, sq = 0.f;
        for (int r = 0; r < 100; ++r) {
            const float v = agg[r * 132 + tid];
            sm += v; sq += v * v;
        }
        atomicAdd(&stats[tid], sm);
        atomicAdd(&stats[128 + tid], sq);
    }
}

// ---------------------------------------------------------------------------
// fuse (BN1+BN2[node_idx]+relu) + bf16 split -> A3, and subgraph-mean -> XS.
// One block per original node (g,n): 50 subgraph-copy rows x 128 ch.
// ---------------------------------------------------------------------------
template <bool FUSE>
__global__ __launch_bounds__(256)
void fusexsum_kernel(const float* __restrict__ HP,
                     const float* __restrict__ H2,
                     const float* __restrict__ prm,
                     unsigned short* __restrict__ A3,
                     unsigned short* __restrict__ XS)
{
    __shared__ float red[256];
    const int blk = blockIdx.x;          // g*50 + n
    const int g = blk / 50, n = blk - g * 50;
    const int tid = threadIdx.x;
    const int c = tid & 127, sh = tid >> 7;
    float a1 = 0.f, c1 = 0.f, hh = 0.f;
    if (FUSE) {
        a1 = prm[c]; c1 = prm[128 + c];
        const float a2 = prm[256 + c], c2 = prm[384 + c];
        hh = a2 * H2[(size_t)blk * 128 + c] + c2;
    }
    float accum = 0.f;
    const int s0 = sh * 25;
    for (int s = s0; s < s0 + 25; ++s) {
        const size_t row = (size_t)g * 2500 + s * 50 + n;
        float v = HP[row * 128 + c];
        if (FUSE) v = fmaxf(0.f, a1 * v + c1 + hh);
        const unsigned short hi = f2bf(v);
        const unsigned short lo = f2bf(v - bf2f(hi));
        A3[row * 256 + c] = hi;
        A3[row * 256 + 128 + c] = lo;
        accum += v;
    }
    red[tid] = accum;
    __syncthreads();
    if (tid < 128) {
        const float xv = (red[tid] + red[tid + 128]) * 0.02f;
        const unsigned short hi = f2bf(xv);
        const unsigned short lo = f2bf(xv - bf2f(hi));
        XS[(size_t)blk * 256 + c] = hi;
        XS[(size_t)blk * 256 + 128 + c] = lo;
    }
}

// per-unit CSR build: 50 nodes, 400 edges, all endpoints inside the unit
__global__ void csr_build(const int* __restrict__ src, const int* __restrict__ dst,
                          int* __restrict__ rp, unsigned char* __restrict__ colx)
{
    __shared__ int cnt[50];
    __shared__ int base[51];
    __shared__ short dl[400], sl[400];
    const int u = blockIdx.x, t = threadIdx.x;   // 64 threads
    if (t < 50) cnt[t] = 0;
    __syncthreads();
    for (int e = t; e < 400; e += 64) {
        const int dd = dst[u * 400 + e] - u * 50;
        const int ss = src[u * 400 + e] - u * 50;
        dl[e] = (short)dd; sl[e] = (short)ss;
        atomicAdd(&cnt[dd], 1);
    }
    __syncthreads();
    if (t == 0) {
        int s = 0;
        for (int i = 0; i < 50; ++i) { base[i] = s; s += cnt[i]; }
        base[50] = 400;
    }
    __syncthreads();
    if (t < 51) rp[u * 51 + t] = base[t];
    if (t < 50) cnt[t] = base[t];
    __syncthreads();
    for (int e = t; e < 400; e += 64) {
        const int pos = atomicAdd(&cnt[dl[e]], 1);
        colx[u * 400 + pos] = (unsigned char)sl[e];
    }
}

// build W3T panels: 8 mats (4 node-conv, 4 sub-conv), [256 n][hi|hi|lo] bf16
__global__ void w3t_kernel(const float* __restrict__ Wr, const float* __restrict__ Wn,
                           const float* __restrict__ Wsr, const float* __restrict__ Wsn,
                           unsigned short* __restrict__ W3T)
{
    const int idx = blockIdx.x * 256 + threadIdx.x;  // 8*256*128
    const int m = idx >> 15;
    const int r = idx & 32767;
    const int n = r >> 7, kk = r & 127;
    const float* Wa = (m < 4) ? Wr + (size_t)m * 16384 : Wsr + (size_t)(m - 4) * 16384;
    const float* Wb = (m < 4) ? Wn + (size_t)m * 16384 : Wsn + (size_t)(m - 4) * 16384;
    const float w = (n < 128) ? Wa[kk * 128 + n] : Wb[kk * 128 + (n - 128)];
    const unsigned short hi = f2bf(w);
    const unsigned short lo = f2bf(w - bf2f(hi));
    unsigned short* o = W3T + (size_t)m * 98304 + (size_t)n * 384;
    o[kk] = hi; o[128 + kk] = hi; o[256 + kk] = lo;
}

// finalize BN params: prm = [a1, c1, a2, c2]; re-zero stats
__global__ void bnfin_kernel(float* __restrict__ stats,
                             const float* __restrict__ bng, const float* __restrict__ bnb,
                             const float* __restrict__ bnsg, const float* __restrict__ bnsb,
                             float* __restrict__ prm)
{
    const int tid = threadIdx.x;
    if (tid < 128) {
        const float s = stats[tid], qq = stats[128 + tid];
        const float mu = s / (float)TN;
        const float var = qq / (float)TN - mu * mu;
        const float inv = 1.0f / sqrtf(var + 1e-5f);
        const float a = bng[tid] * inv;
        prm[tid] = a;
        prm[128 + tid] = bnb[tid] - mu * a;
    } else {
        const int c = tid - 128;
        const float s = stats[256 + c], qq = stats[384 + c];
        const float mu = s / (float)NSUB;
        const float var = qq / (float)NSUB - mu * mu;
        const float inv = 1.0f / sqrtf(var + 1e-5f);
        const float a = bnsg[c] * inv;
        prm[256 + c] = a;
        prm[384 + c] = bnsb[c] - mu * a;
    }
    __syncthreads();
    stats[tid] = 0.f;
    stats[256 + tid] = 0.f;
}

// graph pooling from XS (= mean over s of final x): mean over n
__global__ void pool_kernel(const unsigned short* __restrict__ XS, float* __restrict__ hg)
{
    const int g = blockIdx.x, c = threadIdx.x;   // 128 threads
    float s = 0.f;
    for (int n = 0; n < 50; ++n) {
        const unsigned short* pp = XS + (size_t)(g * 50 + n) * 256;
        s += bf2f(pp[c]) + bf2f(pp[128 + c]);
    }
    hg[g * 128 + c] = s * 0.02f;
}

__global__ void mlp_kernel(const float* __restrict__ hg,
                           const float* __restrict__ W1, const float* __restrict__ b1,
                           const float* __restrict__ W2, const float* __restrict__ b2,
                           float* __restrict__ out)
{
    __shared__ float xv[128];
    __shared__ float hid[256];
    const int g = blockIdx.x, tid = threadIdx.x;
    if (tid < 128) xv[tid] = hg[g * 128 + tid];
    __syncthreads();
    float a = b1[tid];
    for (int k = 0; k < 128; ++k) a += xv[k] * W1[k * 256 + tid];
    hid[tid] = fmaxf(a, 0.f);
    __syncthreads();
    if (tid < 10) {
        float o = b2[tid];
        for (int k = 0; k < 256; ++k) o += hid[k] * W2[k * 10 + tid];
        out[g * 10 + tid] = o;
    }
}

__global__ void zero_kernel(float* __restrict__ pz, int n)
{
    const int t = blockIdx.x * 256 + threadIdx.x;
    if (t < n) pz[t] = 0.f;
}

extern "C" void kernel_launch(void* const* d_in, const int* in_sizes, int n_in,
                              void* d_out, int out_size, void* d_ws, size_t ws_size,
                              hipStream_t stream)
{
    const float* x0   = (const float*)d_in[0];
    const float* Wr   = (const float*)d_in[1];
    const float* Wn   = (const float*)d_in[2];
    const float* bb   = (const float*)d_in[3];
    const float* bng  = (const float*)d_in[4];
    const float* bnb  = (const float*)d_in[5];
    const float* Wsr  = (const float*)d_in[6];
    const float* Wsn  = (const float*)d_in[7];
    const float* bs   = (const float*)d_in[8];
    const float* bnsg = (const float*)d_in[9];
    const float* bnsb = (const float*)d_in[10];
    const float* fW1  = (const float*)d_in[11];
    const float* fb1  = (const float*)d_in[12];
    const float* fW2  = (const float*)d_in[13];
    const float* fb2  = (const float*)d_in[14];
    const int* ei     = (const int*)d_in[15];
    const int* oei    = (const int*)d_in[16];
    float* out        = (float*)d_out;

    char* w = (char*)d_ws;
    unsigned short* A3  = (unsigned short*)w; w += (size_t)TN * 256 * 2;
    float* H1           = (float*)w;          w += (size_t)TN * 128 * 4;
    unsigned short* W3T = (unsigned short*)w; w += (size_t)8 * 98304 * 2;
    unsigned short* XS  = (unsigned short*)w; w += (size_t)NSUB * 256 * 2;
    float* H2           = (float*)w;          w += (size_t)NSUB * 128 * 4;
    int* rps            = (int*)w;            w += (size_t)NSUB * 51 * 4;
    unsigned char* cls  = (unsigned char*)w;  w += (size_t)NSUB * 400;
    int* rpo            = (int*)w;            w += (size_t)GG * 51 * 4;
    unsigned char* clo  = (unsigned char*)w;  w += (size_t)GG * 400;
    float* stats        = (float*)w;          w += 512 * 4;
    float* prm          = (float*)w;          w += 512 * 4;
    float* hg           = (float*)w;          w += (size_t)GG * 128 * 4;

    w3t_kernel<<<1024, 256, 0, stream>>>(Wr, Wn, Wsr, Wsn, W3T);
    csr_build<<<NSUB, 64, 0, stream>>>(ei, ei + 1280000, rps, cls);
    csr_build<<<GG, 64, 0, stream>>>(oei, oei + 25600, rpo, clo);
    zero_kernel<<<2, 256, 0, stream>>>(stats, 512);
    fusexsum_kernel<false><<<NSUB, 256, 0, stream>>>(x0, nullptr, nullptr, A3, XS);

    for (int i = 0; i < NL; ++i) {
        gconv_kernel<<<TN / 100, 256, 0, stream>>>(A3, W3T + (size_t)i * 98304,
                                                   bb + i * 128, rps, cls, H1, stats);
        gconv_kernel<<<NSUB / 100, 256, 0, stream>>>(XS, W3T + (size_t)(4 + i) * 98304,
                                                     bs + i * 128, rpo, clo, H2, stats + 256);
        bnfin_kernel<<<1, 256, 0, stream>>>(stats, bng + i * 128, bnb + i * 128,
                                            bnsg + i * 128, bnsb + i * 128, prm);
        fusexsum_kernel<true><<<NSUB, 256, 0, stream>>>(H1, H2, prm, A3, XS);
    }

    pool_kernel<<<GG, 128, 0, stream>>>(XS, hg);
    mlp_kernel<<<GG, 256, 0, stream>>>(hg, fW1, fb1, fW2, fb2, out);
}

// Round 3
// 975.538 us; speedup vs baseline: 7.8900x; 1.0868x over previous
//
#include <hip/hip_runtime.h>
#include <stdint.h>

#define D 128
#define TN 160000
#define NSUB 3200
#define GG 64
#define NL 4

typedef __bf16 bf16x8 __attribute__((ext_vector_type(8)));
typedef float f32x4 __attribute__((ext_vector_type(4)));
typedef unsigned int u32x4 __attribute__((ext_vector_type(4)));

__device__ __forceinline__ unsigned short f2bf(float v) {
    union { float f; uint32_t u; } c; c.f = v;
    uint32_t r = c.u + 0x7fffu + ((c.u >> 16) & 1u);
    return (unsigned short)(r >> 16);
}
__device__ __forceinline__ float bf2f(unsigned short h) {
    union { float f; uint32_t u; } c; c.u = ((uint32_t)h) << 16;
    return c.f;
}

__device__ __forceinline__ void gload16(const void* g, void* l) {
    __builtin_amdgcn_global_load_lds(
        (const __attribute__((address_space(1))) unsigned int*)g,
        (__attribute__((address_space(3))) unsigned int*)l, 16, 0, 0);
}

// ---------------------------------------------------------------------------
// Fused GraphConv via MFMA. Block = 2 units (100 rows pad 112) x 256 cols.
// A3: [M][256] bf16 = [hi|lo] of x.  W3T per matrix: 8 tiles [256 n][32 k]:
// tiles 0-3 = hi(W) k-slices, tiles 4-7 = lo(W) k-slices (n<128: Wr, else Wn).
// Virtual K = 384: hi*Whi + lo*Whi + hi*Wlo.  B staged once per tile; the
// hi/lo A-substeps share the staged tile and the B fragments (registers).
// Epilogue: Yn -> LDS, CSR aggregation, H = Yr+agg+bias -> global;
// BN sum/sumsq -> 64-way replicated global atomics (no hot lines).
// ---------------------------------------------------------------------------
__global__ __launch_bounds__(256, 2)
void gconv_kernel(const unsigned short* __restrict__ A3,
                  const unsigned short* __restrict__ Wt,
                  const float* __restrict__ bias,
                  const int* __restrict__ rp,
                  const unsigned char* __restrict__ colx,
                  float* __restrict__ H,
                  float* __restrict__ stats)
{
    __shared__ __align__(16) unsigned short Alds[112 * 32];   // 7 KB
    __shared__ __align__(16) unsigned short Blds[256 * 32];   // 16 KB
    __shared__ float agg[100 * 132];                          // 52.8 KB
    __shared__ int rpl[102];
    __shared__ unsigned char coll[800];

    const int tid = threadIdx.x;
    const int blk = blockIdx.x;
    const int rowbase = blk * 100;
    const int lane = tid & 63, wv = tid >> 6;
    const int wvbase = wv * 64;
    const int p = lane & 15, q = lane >> 4;
    const int wn0 = wv * 64;

    // zero the 12 pad rows of Alds once (rows 100..111 never staged)
    if (tid < 192) ((float*)(Alds + 100 * 32))[tid] = 0.f;
    if (tid < 102) rpl[tid] = rp[blk * 102 + tid];
    if (tid < 200) ((uint32_t*)coll)[tid] = ((const uint32_t*)(colx + (size_t)blk * 800))[tid];

    f32x4 acc[7][4];
#pragma unroll
    for (int i = 0; i < 7; ++i)
#pragma unroll
        for (int j = 0; j < 4; ++j) acc[i][j] = (f32x4){0.f, 0.f, 0.f, 0.f};

    bf16x8 bfr[4];

    for (int bs = 0; bs < 8; ++bs) {
        // stage B tile bs: 1024 x 16B, linear copy (wave-uniform LDS base)
#pragma unroll
        for (int rr = 0; rr < 4; ++rr) {
            const int cb = rr * 256 + wvbase;
            gload16(Wt + (size_t)bs * 8192 + (size_t)(cb + lane) * 8, Blds + cb * 8);
        }
        const int na = (bs < 4) ? 2 : 1;
        for (int a = 0; a < na; ++a) {
            const int ka = (bs < 4) ? (bs * 32 + a * 128) : ((bs - 4) * 32);
            // stage A tile: 400 x 16B (chunk c = row*4+qq), wave-uniform base
            {
                const int c = wvbase + lane;
                const int r = c >> 2, qq = c & 3;
                gload16(A3 + (size_t)(rowbase + r) * 256 + ka + qq * 8, Alds + wvbase * 8);
            }
            {
                const int cb = 256 + wvbase;
                const int c = cb + lane;
                if (c < 400) {
                    const int r = c >> 2, qq = c & 3;
                    gload16(A3 + (size_t)(rowbase + r) * 256 + ka + qq * 8, Alds + cb * 8);
                }
            }
            __syncthreads();

            if (a == 0) {
#pragma unroll
                for (int ni = 0; ni < 4; ++ni) {
                    u32x4 raw = *(const u32x4*)&Blds[(wn0 + ni * 16 + p) * 32 + q * 8];
                    bfr[ni] = __builtin_bit_cast(bf16x8, raw);
                }
            }
#pragma unroll
            for (int mi = 0; mi < 7; ++mi) {
                u32x4 raw = *(const u32x4*)&Alds[(mi * 16 + p) * 32 + q * 8];
                bf16x8 afr = __builtin_bit_cast(bf16x8, raw);
#pragma unroll
                for (int ni = 0; ni < 4; ++ni)
                    acc[mi][ni] = __builtin_amdgcn_mfma_f32_16x16x32_bf16(afr, bfr[ni], acc[mi][ni], 0, 0, 0);
            }
            __syncthreads();
        }
    }

    // ---- epilogue ----
    // waves 2,3 hold Yn (cols 128:256): dump to agg LDS
    if (wv >= 2) {
#pragma unroll
        for (int mi = 0; mi < 7; ++mi)
#pragma unroll
            for (int r = 0; r < 4; ++r) {
                const int row = mi * 16 + q * 4 + r;
                if (row < 100) {
#pragma unroll
                    for (int ni = 0; ni < 4; ++ni)
                        agg[row * 132 + (wn0 - 128) + ni * 16 + p] = acc[mi][ni][r];
                }
            }
    }
    __syncthreads();

    // waves 0,1 hold Yr (cols 0:128): CSR aggregate + bias, write H
    if (wv < 2) {
#pragma unroll
        for (int mi = 0; mi < 7; ++mi)
#pragma unroll
            for (int r = 0; r < 4; ++r) {
                const int row = mi * 16 + q * 4 + r;
                if (row >= 100) continue;
                const int ul = row >= 50 ? 1 : 0;
                const int dl = row - ul * 50;
                const int e0 = rpl[ul * 51 + dl], e1 = rpl[ul * 51 + dl + 1];
                float s0 = 0.f, s1 = 0.f, s2 = 0.f, s3 = 0.f;
                for (int e = e0; e < e1; ++e) {
                    const int sr = (int)coll[ul * 400 + e] + ul * 50;
                    s0 += agg[sr * 132 + wn0 + p];
                    s1 += agg[sr * 132 + wn0 + 16 + p];
                    s2 += agg[sr * 132 + wn0 + 32 + p];
                    s3 += agg[sr * 132 + wn0 + 48 + p];
                }
#pragma unroll
                for (int ni = 0; ni < 4; ++ni) {
                    const float sv = (ni == 0) ? s0 : (ni == 1) ? s1 : (ni == 2) ? s2 : s3;
                    const int cc = wn0 + ni * 16 + p;
                    const float h = acc[mi][ni][r] + sv + bias[cc];
                    acc[mi][ni][r] = h;
                    H[(size_t)(rowbase + row) * 128 + cc] = h;
                }
            }
    }
    __syncthreads();
    // waves 0,1 overwrite agg (Yn dead) with H for the stat reduce
    if (wv < 2) {
#pragma unroll
        for (int mi = 0; mi < 7; ++mi)
#pragma unroll
            for (int r = 0; r < 4; ++r) {
                const int row = mi * 16 + q * 4 + r;
                if (row < 100) {
#pragma unroll
                    for (int ni = 0; ni < 4; ++ni)
                        agg[row * 132 + wn0 + ni * 16 + p] = acc[mi][ni][r];
                }
            }
    }
    __syncthreads();
    // all 256 threads: stats partials -> replica (blk & 63)
    {
        const int c = tid & 127;
        const int r0 = (tid >> 7) * 50;
        float sm = 0.f, sq = 0.f;
        for (int r = r0; r < r0 + 50; ++r) {
            const float v = agg[r * 132 + c];
            sm += v; sq += v * v;
        }
        float* rep = stats + (size_t)(blk & 63) * 256;
        atomicAdd(&rep[c], sm);
        atomicAdd(&rep[128 + c], sq);
    }
}

// ---------------------------------------------------------------------------
// fuse (BN1+BN2[node_idx]+relu) + bf16 split -> A3, and subgraph-mean -> XS.
// One block per original node (g,n): 50 subgraph-copy rows x 128 ch.
// ---------------------------------------------------------------------------
template <bool FUSE>
__global__ __launch_bounds__(256)
void fusexsum_kernel(const float* __restrict__ HP,
                     const float* __restrict__ H2,
                     const float* __restrict__ prm,
                     unsigned short* __restrict__ A3,
                     unsigned short* __restrict__ XS)
{
    __shared__ float red[256];
    const int blk = blockIdx.x;          // g*50 + n
    const int g = blk / 50, n = blk - g * 50;
    const int tid = threadIdx.x;
    const int c = tid & 127, sh = tid >> 7;
    float a1 = 0.f, c1 = 0.f, hh = 0.f;
    if (FUSE) {
        a1 = prm[c]; c1 = prm[128 + c];
        const float a2 = prm[256 + c], c2 = prm[384 + c];
        hh = a2 * H2[(size_t)blk * 128 + c] + c2;
    }
    float accum = 0.f;
    const int s0 = sh * 25;
    for (int s = s0; s < s0 + 25; ++s) {
        const size_t row = (size_t)g * 2500 + s * 50 + n;
        float v = HP[row * 128 + c];
        if (FUSE) v = fmaxf(0.f, a1 * v + c1 + hh);
        const unsigned short hi = f2bf(v);
        const unsigned short lo = f2bf(v - bf2f(hi));
        A3[row * 256 + c] = hi;
        A3[row * 256 + 128 + c] = lo;
        accum += v;
    }
    red[tid] = accum;
    __syncthreads();
    if (tid < 128) {
        const float xv = (red[tid] + red[tid + 128]) * 0.02f;
        const unsigned short hi = f2bf(xv);
        const unsigned short lo = f2bf(xv - bf2f(hi));
        XS[(size_t)blk * 256 + c] = hi;
        XS[(size_t)blk * 256 + 128 + c] = lo;
    }
}

// per-unit CSR build: 50 nodes, 400 edges, all endpoints inside the unit
__global__ void csr_build(const int* __restrict__ src, const int* __restrict__ dst,
                          int* __restrict__ rp, unsigned char* __restrict__ colx)
{
    __shared__ int cnt[50];
    __shared__ int base[51];
    __shared__ short dl[400], sl[400];
    const int u = blockIdx.x, t = threadIdx.x;   // 64 threads
    if (t < 50) cnt[t] = 0;
    __syncthreads();
    for (int e = t; e < 400; e += 64) {
        const int dd = dst[u * 400 + e] - u * 50;
        const int ss = src[u * 400 + e] - u * 50;
        dl[e] = (short)dd; sl[e] = (short)ss;
        atomicAdd(&cnt[dd], 1);
    }
    __syncthreads();
    if (t == 0) {
        int s = 0;
        for (int i = 0; i < 50; ++i) { base[i] = s; s += cnt[i]; }
        base[50] = 400;
    }
    __syncthreads();
    if (t < 51) rp[u * 51 + t] = base[t];
    if (t < 50) cnt[t] = base[t];
    __syncthreads();
    for (int e = t; e < 400; e += 64) {
        const int pos = atomicAdd(&cnt[dl[e]], 1);
        colx[u * 400 + pos] = (unsigned char)sl[e];
    }
}

// build W3T: 8 matrices x 8 tiles x [256 n][32 k] bf16; tiles 0-3 hi, 4-7 lo
__global__ void w3t_kernel(const float* __restrict__ Wr, const float* __restrict__ Wn,
                           const float* __restrict__ Wsr, const float* __restrict__ Wsn,
                           unsigned short* __restrict__ W3T)
{
    const int idx = blockIdx.x * 256 + threadIdx.x;  // 8*65536
    const int m = idx >> 16;
    const int r = idx & 65535;
    const int bt = r >> 13;
    const int rr = r & 8191;
    const int n = rr >> 5, kloc = rr & 31;
    const int kg = (bt & 3) * 32 + kloc;
    const float* Wa = (m < 4) ? Wr + (size_t)m * 16384 : Wsr + (size_t)(m - 4) * 16384;
    const float* Wb = (m < 4) ? Wn + (size_t)m * 16384 : Wsn + (size_t)(m - 4) * 16384;
    const float w = (n < 128) ? Wa[kg * 128 + n] : Wb[kg * 128 + (n - 128)];
    const unsigned short hi = f2bf(w);
    W3T[idx] = (bt < 4) ? hi : f2bf(w - bf2f(hi));
}

// finalize BN params from 64-replica stats; prm = [a1,c1,a2,c2]; re-zero reps
__global__ void bnfin_kernel(float* __restrict__ stats,
                             const float* __restrict__ bng, const float* __restrict__ bnb,
                             const float* __restrict__ bnsg, const float* __restrict__ bnsb,
                             float* __restrict__ prm)
{
    __shared__ float sN[256], sS[256];
    const int tid = threadIdx.x;
    float aN = 0.f, aS = 0.f;
    for (int r = 0; r < 64; ++r) {
        aN += stats[r * 256 + tid];
        aS += stats[16384 + r * 256 + tid];
    }
    sN[tid] = aN; sS[tid] = aS;
    __syncthreads();
    if (tid < 128) {
        const float mu = sN[tid] / (float)TN;
        const float var = sN[128 + tid] / (float)TN - mu * mu;
        const float a = bng[tid] / sqrtf(var + 1e-5f);
        prm[tid] = a;
        prm[128 + tid] = bnb[tid] - mu * a;
    } else {
        const int c = tid - 128;
        const float mu = sS[c] / (float)NSUB;
        const float var = sS[128 + c] / (float)NSUB - mu * mu;
        const float a = bnsg[c] / sqrtf(var + 1e-5f);
        prm[256 + c] = a;
        prm[384 + c] = bnsb[c] - mu * a;
    }
    for (int i = tid; i < 32768; i += 256) stats[i] = 0.f;
}

// graph pooling from XS: mean over n
__global__ void pool_kernel(const unsigned short* __restrict__ XS, float* __restrict__ hg)
{
    const int g = blockIdx.x, c = threadIdx.x;   // 128 threads
    float s = 0.f;
    for (int n = 0; n < 50; ++n) {
        const unsigned short* pp = XS + (size_t)(g * 50 + n) * 256;
        s += bf2f(pp[c]) + bf2f(pp[128 + c]);
    }
    hg[g * 128 + c] = s * 0.02f;
}

__global__ void mlp_kernel(const float* __restrict__ hg,
                           const float* __restrict__ W1, const float* __restrict__ b1,
                           const float* __restrict__ W2, const float* __restrict__ b2,
                           float* __restrict__ out)
{
    __shared__ float xv[128];
    __shared__ float hid[256];
    const int g = blockIdx.x, tid = threadIdx.x;
    if (tid < 128) xv[tid] = hg[g * 128 + tid];
    __syncthreads();
    float a = b1[tid];
    for (int k = 0; k < 128; ++k) a += xv[k] * W1[k * 256 + tid];
    hid[tid] = fmaxf(a, 0.f);
    __syncthreads();
    if (tid < 10) {
        float o = b2[tid];
        for (int k = 0; k < 256; ++k) o += hid[k] * W2[k * 10 + tid];
        out[g * 10 + tid] = o;
    }
}

__global__ void zero_kernel(float* __restrict__ pz, int n)
{
    const int t = blockIdx.x * 256 + threadIdx.x;
    if (t < n) pz[t] = 0.f;
}

extern "C" void kernel_launch(void* const* d_in, const int* in_sizes, int n_in,
                              void* d_out, int out_size, void* d_ws, size_t ws_size,
                              hipStream_t stream)
{
    const float* x0   = (const float*)d_in[0];
    const float* Wr   = (const float*)d_in[1];
    const float* Wn   = (const float*)d_in[2];
    const float* bb   = (const float*)d_in[3];
    const float* bng  = (const float*)d_in[4];
    const float* bnb  = (const float*)d_in[5];
    const float* Wsr  = (const float*)d_in[6];
    const float* Wsn  = (const float*)d_in[7];
    const float* bs   = (const float*)d_in[8];
    const float* bnsg = (const float*)d_in[9];
    const float* bnsb = (const float*)d_in[10];
    const float* fW1  = (const float*)d_in[11];
    const float* fb1  = (const float*)d_in[12];
    const float* fW2  = (const float*)d_in[13];
    const float* fb2  = (const float*)d_in[14];
    const int* ei     = (const int*)d_in[15];
    const int* oei    = (const int*)d_in[16];
    float* out        = (float*)d_out;

    char* w = (char*)d_ws;
    unsigned short* A3  = (unsigned short*)w; w += (size_t)TN * 256 * 2;
    float* H1           = (float*)w;          w += (size_t)TN * 128 * 4;
    unsigned short* W3T = (unsigned short*)w; w += (size_t)8 * 65536 * 2;
    unsigned short* XS  = (unsigned short*)w; w += (size_t)NSUB * 256 * 2;
    float* H2           = (float*)w;          w += (size_t)NSUB * 128 * 4;
    int* rps            = (int*)w;            w += (size_t)NSUB * 51 * 4;
    unsigned char* cls  = (unsigned char*)w;  w += (size_t)NSUB * 400;
    int* rpo            = (int*)w;            w += (size_t)GG * 51 * 4;
    unsigned char* clo  = (unsigned char*)w;  w += (size_t)GG * 400;
    float* stats        = (float*)w;          w += (size_t)32768 * 4;  // [2][64][256]
    float* prm          = (float*)w;          w += 512 * 4;
    float* hg           = (float*)w;          w += (size_t)GG * 128 * 4;

    w3t_kernel<<<2048, 256, 0, stream>>>(Wr, Wn, Wsr, Wsn, W3T);
    csr_build<<<NSUB, 64, 0, stream>>>(ei, ei + 1280000, rps, cls);
    csr_build<<<GG, 64, 0, stream>>>(oei, oei + 25600, rpo, clo);
    zero_kernel<<<128, 256, 0, stream>>>(stats, 32768);
    fusexsum_kernel<false><<<NSUB, 256, 0, stream>>>(x0, nullptr, nullptr, A3, XS);

    for (int i = 0; i < NL; ++i) {
        gconv_kernel<<<TN / 100, 256, 0, stream>>>(A3, W3T + (size_t)i * 65536,
                                                   bb + i * 128, rps, cls, H1, stats);
        gconv_kernel<<<NSUB / 100, 256, 0, stream>>>(XS, W3T + (size_t)(4 + i) * 65536,
                                                     bs + i * 128, rpo, clo, H2, stats + 16384);
        bnfin_kernel<<<1, 256, 0, stream>>>(stats, bng + i * 128, bnb + i * 128,
                                            bnsg + i * 128, bnsb + i * 128, prm);
        fusexsum_kernel<true><<<NSUB, 256, 0, stream>>>(H1, H2, prm, A3, XS);
    }

    pool_kernel<<<GG, 128, 0, stream>>>(XS, hg);
    mlp_kernel<<<GG, 256, 0, stream>>>(hg, fW1, fb1, fW2, fb2, out);
}